// Round 7
// baseline (70.292 us; speedup 1.0000x reference)
//
#include <hip/hip_runtime.h>
#include <math.h>
#include <stdint.h>

// Problem constants (from reference)
#define BATCH      1024
#define NB_REQ     8
#define INPUT_DIM  512
#define MAX_DEPTH  17
#define NB_CLASSES 100000
#define N_NODES    (NB_CLASSES - 1)
#define ITEMS      (BATCH * NB_REQ * MAX_DEPTH)   // 139264
#define CAP        16

typedef float     f4 __attribute__((ext_vector_type(4)));
typedef _Float16  h8 __attribute__((ext_vector_type(8)));

// ---------------------------------------------------------------------------
// Node-inverted v4.
//  - cnt zeroed by hipMemsetAsync (graph-capturable); x->fp16 conversion
//    fused into build: 3 kernels + 1 memset (was 4 kernels).
//  - nt hint ONLY on the two W-row loads in main (strictly one-touch stream;
//    evict-first so the 1 MB xh + bias + cnt stay L2-resident).
//    R5 showed nt on reused paths (slots/fact) is harmful; W is the only
//    true stream here.
// ---------------------------------------------------------------------------

__global__ __launch_bounds__(256) void build_kernel(
    const float* __restrict__ x,         // (BATCH, INPUT_DIM)
    const int*   __restrict__ targets,   // (BATCH, NB_REQ)
    const int*   __restrict__ path,      // (NB_CLASSES, MAX_DEPTH)
    const float* __restrict__ codes,     // (NB_CLASSES, MAX_DEPTH)
    _Float16*    __restrict__ xh,        // (BATCH, INPUT_DIM) fp16 out
    uint32_t*    __restrict__ cnt,       // (N_NODES,) pre-zeroed
    uint32_t*    __restrict__ slots)     // (N_NODES, CAP), entry = (t<<1)|h
{
    const int t = blockIdx.x * 256 + threadIdx.x;      // grid exact: 139264

    // Fused x conversion: threads 0..131071 convert 4 floats each.
    if (t < (BATCH * INPUT_DIM) / 4) {
        const f4 v = *reinterpret_cast<const f4*>(x + (size_t)t * 4);
        _Float16 hh[4] = { (_Float16)v.x, (_Float16)v.y,
                           (_Float16)v.z, (_Float16)v.w };
        *reinterpret_cast<uint2*>(xh + (size_t)t * 4) =
            *reinterpret_cast<const uint2*>(hh);
    }

    if (t >= ITEMS) return;
    const int pair = t / MAX_DEPTH;
    const int d    = t - pair * MAX_DEPTH;
    const int cls  = targets[pair];
    const int   node = path [(size_t)cls * MAX_DEPTH + d];
    const float hf   = codes[(size_t)cls * MAX_DEPTH + d];
    const uint32_t entry = ((uint32_t)t << 1) | (hf != 0.0f ? 1u : 0u);
    const uint32_t pos = atomicAdd(&cnt[node], 1u);
    if (pos < CAP) slots[(size_t)node * CAP + pos] = entry;
}

__global__ __launch_bounds__(256) void main_kernel(
    const _Float16* __restrict__ xh,     // fp16 x, L2-resident (1 MB)
    const float*    __restrict__ W,      // (N_NODES, INPUT_DIM) one-touch stream
    const float*    __restrict__ bias,   // (N_NODES,)
    const uint32_t* __restrict__ cnt,
    const uint32_t* __restrict__ slots,
    float*          __restrict__ fact)   // (ITEMS,)
{
    const int wave = threadIdx.x >> 6;
    const int lane = threadIdx.x & 63;
    const int node = blockIdx.x * 4 + wave;
    if (node >= N_NODES) return;

    const uint32_t c0 = cnt[node];
    const int c = __builtin_amdgcn_readfirstlane((int)(c0 > CAP ? CAP : c0));
    if (c == 0) return;

    // W row fetched once; nt = evict-first so it doesn't displace xh in L2.
    const f4* wrow = reinterpret_cast<const f4*>(W + (size_t)node * INPUT_DIM);
    const f4 w0 = __builtin_nontemporal_load(&wrow[lane * 2 + 0]);
    const f4 w1 = __builtin_nontemporal_load(&wrow[lane * 2 + 1]);
    const float bv = bias[node];

    // First 4 slot entries in one 16B load (uniform address).
    const uint4 s4 = *reinterpret_cast<const uint4*>(slots + (size_t)node * CAP);

    for (int j = 0; j < c; ++j) {
        uint32_t e;
        if (j < 4) {
            e = (j == 0) ? s4.x : (j == 1) ? s4.y : (j == 2) ? s4.z : s4.w;
        } else {
            e = slots[(size_t)node * CAP + j];
        }
        e = (uint32_t)__builtin_amdgcn_readfirstlane((int)e);

        const int   t    = (int)(e >> 1);
        const float hf   = (float)(e & 1u);
        const int   pair = (int)((uint32_t)t / (uint32_t)MAX_DEPTH);
        const int   bi   = pair >> 3;

        // x row: 1 KB fp16, should be an L2 hit.
        const h8 xv = reinterpret_cast<const h8*>(xh + (size_t)bi * INPUT_DIM)[lane];
        float acc = (float)xv[0] * w0.x + (float)xv[1] * w0.y
                  + (float)xv[2] * w0.z + (float)xv[3] * w0.w
                  + (float)xv[4] * w1.x + (float)xv[5] * w1.y
                  + (float)xv[6] * w1.z + (float)xv[7] * w1.w;

        #pragma unroll
        for (int off = 32; off >= 1; off >>= 1)
            acc += __shfl_xor(acc, off, 64);

        const float p = 1.0f / (1.0f + __expf(-(acc + bv)));
        const float f = hf + p - 2.0f * hf * p;     // p if h==0 else 1-p

        if (lane == 0) fact[t] = f;
    }
}

__global__ __launch_bounds__(256) void finalize_kernel(
    const float* __restrict__ fact,    // (ITEMS,)
    float*       __restrict__ out)     // (BATCH*NB_REQ,)
{
    const int pair = blockIdx.x * 256 + threadIdx.x;   // grid exact: 8192
    float prod = 1.0f;
    #pragma unroll
    for (int d = 0; d < MAX_DEPTH; ++d)
        prod *= fact[(size_t)pair * MAX_DEPTH + d];
    out[pair] = prod;
}

extern "C" void kernel_launch(void* const* d_in, const int* in_sizes, int n_in,
                              void* d_out, int out_size, void* d_ws, size_t ws_size,
                              hipStream_t stream) {
    const float* x       = (const float*)d_in[0];  // input_vector (1024, 512)
    const int*   targets = (const int*)  d_in[1];  // target_classes (1024, 8)
    const float* W       = (const float*)d_in[2];  // W (99999, 512)
    const float* bias    = (const float*)d_in[3];  // b (99999,)
    const int*   path    = (const int*)  d_in[4];  // class_path_map (100000, 17)
    const float* codes   = (const float*)d_in[5];  // huffman_codes (100000, 17)
    float*       out     = (float*)d_out;          // (1024, 8)

    // Workspace layout (~8.4 MB; ws is larger).
    uint32_t* cnt   = (uint32_t*)d_ws;                         // 100000 u32
    uint32_t* slots = cnt + 100000;                            // 100000*16 u32
    float*    fact  = (float*)(slots + (size_t)100000 * CAP);  // 139264 f32
    _Float16* xh    = (_Float16*)(fact + ITEMS);               // 524288 f16

    hipMemsetAsync(cnt, 0, (size_t)100000 * sizeof(uint32_t), stream);
    build_kernel   <<<(ITEMS + 255) / 256, 256, 0, stream>>>(x, targets, path, codes,
                                                             xh, cnt, slots);
    main_kernel    <<<(N_NODES + 3) / 4,   256, 0, stream>>>(xh, W, bias,
                                                             cnt, slots, fact);
    finalize_kernel<<<BATCH * NB_REQ / 256, 256, 0, stream>>>(fact, out);
}

// Round 8
// 64.544 us; speedup vs baseline: 1.0891x; 1.0891x over previous
//
#include <hip/hip_runtime.h>
#include <math.h>
#include <stdint.h>

// Problem constants (from reference)
#define BATCH      1024
#define NB_REQ     8
#define INPUT_DIM  512
#define MAX_DEPTH  17
#define NB_CLASSES 100000
#define N_NODES    (NB_CLASSES - 1)
#define ITEMS      (BATCH * NB_REQ * MAX_DEPTH)   // 139264
#define CAP        16
#define MAIN_BLOCKS 1024
#define MAIN_WAVES  (MAIN_BLOCKS * 4)             // 4096 waves, grid-strided

typedef float     f4 __attribute__((ext_vector_type(4)));
typedef _Float16  h8 __attribute__((ext_vector_type(8)));

// ---------------------------------------------------------------------------
// Node-inverted v5.
//  - NO nontemporal hints anywhere (R5: -8us, R7: -15us — nt loads are just
//    slower on gfx950).
//  - main is grid-strided + 2-stage software pipelined: cnt/slots prefetched
//    2 nodes ahead, W row (conditional on c>0) 1 node ahead => W HBM latency
//    (~900cy) hidden under a full node-iteration; stream stays in flight.
//  - x kept as fp16 (1 MB, L2-resident); h-bit packed in slot entry.
// ---------------------------------------------------------------------------

__global__ __launch_bounds__(256) void build_kernel(
    const float* __restrict__ x,         // (BATCH, INPUT_DIM)
    const int*   __restrict__ targets,   // (BATCH, NB_REQ)
    const int*   __restrict__ path,      // (NB_CLASSES, MAX_DEPTH)
    const float* __restrict__ codes,     // (NB_CLASSES, MAX_DEPTH)
    _Float16*    __restrict__ xh,        // (BATCH, INPUT_DIM) fp16 out
    uint32_t*    __restrict__ cnt,       // (N_NODES,) pre-zeroed
    uint32_t*    __restrict__ slots)     // (N_NODES, CAP), entry = (t<<1)|h
{
    const int t = blockIdx.x * 256 + threadIdx.x;      // grid exact: 139264

    // Fused x conversion: threads 0..131071 convert 4 floats each.
    if (t < (BATCH * INPUT_DIM) / 4) {
        const f4 v = *reinterpret_cast<const f4*>(x + (size_t)t * 4);
        _Float16 hh[4] = { (_Float16)v.x, (_Float16)v.y,
                           (_Float16)v.z, (_Float16)v.w };
        *reinterpret_cast<uint2*>(xh + (size_t)t * 4) =
            *reinterpret_cast<const uint2*>(hh);
    }

    if (t >= ITEMS) return;
    const int pair = t / MAX_DEPTH;
    const int d    = t - pair * MAX_DEPTH;
    const int cls  = targets[pair];
    const int   node = path [(size_t)cls * MAX_DEPTH + d];
    const float hf   = codes[(size_t)cls * MAX_DEPTH + d];
    const uint32_t entry = ((uint32_t)t << 1) | (hf != 0.0f ? 1u : 0u);
    const uint32_t pos = atomicAdd(&cnt[node], 1u);
    if (pos < CAP) slots[(size_t)node * CAP + pos] = entry;
}

__device__ __forceinline__ void process_item(
    uint32_t e, const _Float16* __restrict__ xh,
    const f4 w0, const f4 w1, const float bv, const int lane,
    float* __restrict__ fact)
{
    e = (uint32_t)__builtin_amdgcn_readfirstlane((int)e);
    const int   t    = (int)(e >> 1);
    const float hfv  = (float)(e & 1u);
    const int   pair = (int)((uint32_t)t / 17u);   // magic-mul
    const int   bi   = pair >> 3;

    const h8 xv = reinterpret_cast<const h8*>(xh + (size_t)bi * INPUT_DIM)[lane];
    float acc = (float)xv[0] * w0.x + (float)xv[1] * w0.y
              + (float)xv[2] * w0.z + (float)xv[3] * w0.w
              + (float)xv[4] * w1.x + (float)xv[5] * w1.y
              + (float)xv[6] * w1.z + (float)xv[7] * w1.w;

    #pragma unroll
    for (int off = 32; off >= 1; off >>= 1)
        acc += __shfl_xor(acc, off, 64);

    const float p = 1.0f / (1.0f + __expf(-(acc + bv)));
    const float f = hfv + p - 2.0f * hfv * p;      // p if h==0 else 1-p
    if (lane == 0) fact[t] = f;
}

__global__ __launch_bounds__(256) void main_kernel(
    const _Float16* __restrict__ xh,     // fp16 x (1 MB), L2-resident
    const float*    __restrict__ W,      // (N_NODES, INPUT_DIM), one-touch
    const float*    __restrict__ bias,   // (N_NODES,)
    const uint32_t* __restrict__ cnt,
    const uint32_t* __restrict__ slots,
    float*          __restrict__ fact)   // (ITEMS,)
{
    const int lane = threadIdx.x & 63;
    const int wid  = blockIdx.x * 4 + (threadIdx.x >> 6);   // 0..MAIN_WAVES-1
    const int S    = MAIN_WAVES;

    // Pipeline: stage A = {cnt,slots} for node n+2S; stage B = full state for n+S.
    uint32_t cB = 0, cA = 0;
    uint4    sB = make_uint4(0,0,0,0), sA = make_uint4(0,0,0,0);
    f4 wB0 = {0,0,0,0}, wB1 = {0,0,0,0};
    float bvB = 0.0f;

    const int nB0 = wid;
    const int nA0 = wid + S;
    if (nB0 < N_NODES) {
        cB = cnt[nB0];
        sB = *reinterpret_cast<const uint4*>(slots + (size_t)nB0 * CAP);
        if (cB) {
            const f4* wr = reinterpret_cast<const f4*>(W + (size_t)nB0 * INPUT_DIM);
            wB0 = wr[lane * 2 + 0];
            wB1 = wr[lane * 2 + 1];
            bvB = bias[nB0];
        }
    }
    if (nA0 < N_NODES) {
        cA = cnt[nA0];
        sA = *reinterpret_cast<const uint4*>(slots + (size_t)nA0 * CAP);
    }

    for (int n = nB0; n < N_NODES; n += S) {
        // current <- stage B
        const int   c  = __builtin_amdgcn_readfirstlane((int)(cB > CAP ? CAP : cB));
        const uint4 s4 = sB;
        const f4    w0 = wB0, w1 = wB1;
        const float bv = bvB;

        // stage B <- stage A; issue its W-row load (1 iteration of slack)
        const int n1 = n + S;
        cB = cA; sB = sA;
        if (n1 < N_NODES && cB) {
            const f4* wr = reinterpret_cast<const f4*>(W + (size_t)n1 * INPUT_DIM);
            wB0 = wr[lane * 2 + 0];
            wB1 = wr[lane * 2 + 1];
            bvB = bias[n1];
        }
        // stage A <- loads for node n+2S (2 iterations of slack)
        const int n2 = n + 2 * S;
        if (n2 < N_NODES) {
            cA = cnt[n2];
            sA = *reinterpret_cast<const uint4*>(slots + (size_t)n2 * CAP);
        }

        // process current node's items (c ~ Poisson(1.39); c<=4 covers 99.9%)
        if (c > 0) {
            #pragma unroll
            for (int j = 0; j < 4; ++j) {
                if (j < c) {
                    const uint32_t e = (j == 0) ? s4.x : (j == 1) ? s4.y
                                     : (j == 2) ? s4.z : s4.w;
                    process_item(e, xh, w0, w1, bv, lane, fact);
                }
            }
            for (int j = 4; j < c; ++j) {          // rare tail, same 64B line
                process_item(slots[(size_t)n * CAP + j], xh, w0, w1, bv, lane, fact);
            }
        }
    }
}

__global__ __launch_bounds__(256) void finalize_kernel(
    const float* __restrict__ fact,    // (ITEMS,)
    float*       __restrict__ out)     // (BATCH*NB_REQ,)
{
    const int pair = blockIdx.x * 256 + threadIdx.x;   // grid exact: 8192
    float prod = 1.0f;
    #pragma unroll
    for (int d = 0; d < MAX_DEPTH; ++d)
        prod *= fact[(size_t)pair * MAX_DEPTH + d];
    out[pair] = prod;
}

extern "C" void kernel_launch(void* const* d_in, const int* in_sizes, int n_in,
                              void* d_out, int out_size, void* d_ws, size_t ws_size,
                              hipStream_t stream) {
    const float* x       = (const float*)d_in[0];  // input_vector (1024, 512)
    const int*   targets = (const int*)  d_in[1];  // target_classes (1024, 8)
    const float* W       = (const float*)d_in[2];  // W (99999, 512)
    const float* bias    = (const float*)d_in[3];  // b (99999,)
    const int*   path    = (const int*)  d_in[4];  // class_path_map (100000, 17)
    const float* codes   = (const float*)d_in[5];  // huffman_codes (100000, 17)
    float*       out     = (float*)d_out;          // (1024, 8)

    // Workspace layout (~8.4 MB; ws is larger).
    uint32_t* cnt   = (uint32_t*)d_ws;                         // 100000 u32
    uint32_t* slots = cnt + 100000;                            // 100000*16 u32
    float*    fact  = (float*)(slots + (size_t)100000 * CAP);  // 139264 f32
    _Float16* xh    = (_Float16*)(fact + ITEMS);               // 524288 f16

    hipMemsetAsync(cnt, 0, (size_t)100000 * sizeof(uint32_t), stream);
    build_kernel   <<<(ITEMS + 255) / 256, 256, 0, stream>>>(x, targets, path, codes,
                                                             xh, cnt, slots);
    main_kernel    <<<MAIN_BLOCKS,          256, 0, stream>>>(xh, W, bias,
                                                              cnt, slots, fact);
    finalize_kernel<<<BATCH * NB_REQ / 256, 256, 0, stream>>>(fact, out);
}

// Round 9
// 48.517 us; speedup vs baseline: 1.4488x; 1.3303x over previous
//
#include <hip/hip_runtime.h>
#include <math.h>

// Problem constants (from reference)
#define BATCH      1024
#define NB_REQ     8
#define INPUT_DIM  512
#define MAX_DEPTH  17

// One wave (64 lanes) per (batch, req) pair. 8192 pairs total.
// Each lane owns 8 contiguous elements of the 512-d vectors.
//
// R1-R8 findings baked in:
//  - This pair-major form runs at 6.27 TB/s effective L2-boundary BW
//    (301 MB / 48 us) = 99.5% of the measured 6.3 TB/s ceiling.
//  - Node-major dedup (1.6x fewer bytes) never beat it: unique-row stream
//    runs ~4 TB/s + ~14 us aux pipeline overhead (best 55 us).
//  - __builtin_nontemporal_load is strictly harmful on gfx950 (-8 to -15 us).
//  - Extra ILP / batched butterflies regress (R2: +2.5 us).
__global__ __launch_bounds__(256) void huffmax_kernel(
    const float* __restrict__ x,        // (BATCH, INPUT_DIM)
    const int*   __restrict__ targets,  // (BATCH, NB_REQ)
    const float* __restrict__ W,        // (N_NODES, INPUT_DIM)
    const float* __restrict__ bias,     // (N_NODES,)
    const int*   __restrict__ path,     // (NB_CLASSES, MAX_DEPTH)
    const float* __restrict__ codes,    // (NB_CLASSES, MAX_DEPTH)
    float*       __restrict__ out)      // (BATCH, NB_REQ)
{
    const int wave = threadIdx.x >> 6;
    const int lane = threadIdx.x & 63;
    const int pair = blockIdx.x * 4 + wave;      // 0 .. 8191
    if (pair >= BATCH * NB_REQ) return;
    const int bi = pair >> 3;                    // batch index

    // Load this batch row of x into registers: 8 floats / lane (2x float4).
    const float4* xrow = reinterpret_cast<const float4*>(x + (long)bi * INPUT_DIM);
    const float4 x0 = xrow[lane * 2 + 0];
    const float4 x1 = xrow[lane * 2 + 1];

    const int cls = targets[pair];
    const int*   prow = path  + (long)cls * MAX_DEPTH;
    const float* hrow = codes + (long)cls * MAX_DEPTH;

    float prod = 1.0f;
    for (int d = 0; d < MAX_DEPTH; ++d) {
        const int node = prow[d];                       // wave-uniform
        const float4* wrow =
            reinterpret_cast<const float4*>(W + (long)node * INPUT_DIM);
        const float4 w0 = wrow[lane * 2 + 0];
        const float4 w1 = wrow[lane * 2 + 1];

        float acc = x0.x * w0.x + x0.y * w0.y + x0.z * w0.z + x0.w * w0.w
                  + x1.x * w1.x + x1.y * w1.y + x1.z * w1.z + x1.w * w1.w;

        // 64-lane butterfly reduce; every lane ends with the full dot.
        #pragma unroll
        for (int off = 32; off > 0; off >>= 1)
            acc += __shfl_xor(acc, off, 64);

        const float y = acc + bias[node];
        const float p = 1.0f / (1.0f + expf(-y));
        const float h = hrow[d];
        prod *= (h + p - 2.0f * h * p);   // p if h==0 else 1-p (matches ref exactly)
    }

    if (lane == 0) out[pair] = prod;
}

extern "C" void kernel_launch(void* const* d_in, const int* in_sizes, int n_in,
                              void* d_out, int out_size, void* d_ws, size_t ws_size,
                              hipStream_t stream) {
    const float* x       = (const float*)d_in[0];  // input_vector (1024, 512)
    const int*   targets = (const int*)  d_in[1];  // target_classes (1024, 8)
    const float* W       = (const float*)d_in[2];  // W (99999, 512)
    const float* bias    = (const float*)d_in[3];  // b (99999,)
    const int*   path    = (const int*)  d_in[4];  // class_path_map (100000, 17)
    const float* codes   = (const float*)d_in[5];  // huffman_codes (100000, 17)
    float*       out     = (float*)d_out;          // (1024, 8)

    const int pairs  = BATCH * NB_REQ;             // 8192
    const int blocks = pairs / 4;                  // 4 waves (pairs) per 256-thr block

    huffmax_kernel<<<blocks, 256, 0, stream>>>(x, targets, W, bias, path, codes, out);
}